// Round 3
// baseline (1690.376 us; speedup 1.0000x reference)
//
#include <hip/hip_runtime.h>

typedef _Float16 f16;
typedef _Float16 h2 __attribute__((ext_vector_type(2)));
typedef _Float16 h8 __attribute__((ext_vector_type(8)));
typedef float    f4 __attribute__((ext_vector_type(4)));

#define S_  256
#define B_  1024
#define D_  64
#define H_  128
#define Z_  32
#define BD_ (B_*D_)
#define NSTEP 514

__device__ __forceinline__ float fdot2(h2 a, h2 b, float c) {
#if __has_builtin(__builtin_amdgcn_fdot2)
  return __builtin_amdgcn_fdot2(a, b, c, false);
#else
  return c + (float)a[0]*(float)b[0] + (float)a[1]*(float)b[1];
#endif
}

__device__ __forceinline__ float dot8(h8 a, h8 w, float acc) {
  h2 a0 = __builtin_shufflevector(a, a, 0, 1), w0 = __builtin_shufflevector(w, w, 0, 1);
  h2 a1 = __builtin_shufflevector(a, a, 2, 3), w1 = __builtin_shufflevector(w, w, 2, 3);
  h2 a2 = __builtin_shufflevector(a, a, 4, 5), w2 = __builtin_shufflevector(w, w, 4, 5);
  h2 a3 = __builtin_shufflevector(a, a, 6, 7), w3 = __builtin_shufflevector(w, w, 6, 7);
  acc = fdot2(a0, w0, acc);
  acc = fdot2(a1, w1, acc);
  acc = fdot2(a2, w2, acc);
  acc = fdot2(a3, w3, acc);
  return acc;
}

__device__ __forceinline__ h8 ld8(const float* p) {   // 16B-aligned src
  f4 a = *(const f4*)p;
  f4 b = *(const f4*)(p + 4);
  h8 w;
  w[0]=(f16)a[0]; w[1]=(f16)a[1]; w[2]=(f16)a[2]; w[3]=(f16)a[3];
  w[4]=(f16)b[0]; w[5]=(f16)b[1]; w[6]=(f16)b[2]; w[7]=(f16)b[3];
  return w;
}

__device__ __forceinline__ float sigm(float x) { return 1.f / (1.f + __expf(-x)); }
__device__ __forceinline__ float tanh_(float x) {
  float e = __expf(-2.f * fabsf(x));
  float t = (1.f - e) / (1.f + e);
  return copysignf(t, x);
}

// ---------------------------------------------------------------------------
// GRU: 1024 blocks x 1 batch row, 256 threads. Role (jh = t&127, kh = t>>7):
// 3 gate rows {jh, jh+128, jh+256}, k-half kh (kh0: h[0:96); kh1: h[96:128)+x).
// Weights in registers (144 VGPR); launch_bounds(256,3) -> 3 blocks/CU.
// ---------------------------------------------------------------------------
__global__ __launch_bounds__(256, 3) void gru_kernel(
    const float* __restrict__ xs, const float* __restrict__ Wih,
    const float* __restrict__ Whh, const float* __restrict__ bih,
    const float* __restrict__ bhh, float* __restrict__ hT)
{
  __shared__ h8 hvv[16];               // h f16 (128)
  __shared__ h8 xvv[8];                // x f16 (64)
  __shared__ float P[2][4][128];       // [kh][r,z,nh,nx][jh]

  const int t    = threadIdx.x;
  const int brow = blockIdx.x;
  const int jh = t & 127;
  const int kh = t >> 7;

  h8 wr[12], wz[12], wn[12];
  if (kh == 0) {               // h cols [0:96)
    #pragma unroll
    for (int c = 0; c < 12; ++c) {
      wr[c] = ld8(Whh + jh*H_        + c*8);
      wz[c] = ld8(Whh + (jh+128)*H_  + c*8);
      wn[c] = ld8(Whh + (jh+256)*H_  + c*8);
    }
  } else {                     // h cols [96:128) then x cols [0:64)
    #pragma unroll
    for (int c = 0; c < 4; ++c) {
      wr[c] = ld8(Whh + jh*H_        + 96 + c*8);
      wz[c] = ld8(Whh + (jh+128)*H_  + 96 + c*8);
      wn[c] = ld8(Whh + (jh+256)*H_  + 96 + c*8);
    }
    #pragma unroll
    for (int c = 0; c < 8; ++c) {
      wr[4+c] = ld8(Wih + jh*D_        + c*8);
      wz[4+c] = ld8(Wih + (jh+128)*D_  + c*8);
      wn[4+c] = ld8(Wih + (jh+256)*D_  + c*8);
    }
  }

  float birr = 0.f, bizz = 0.f, bin = 0.f, bhn = 0.f, hmast = 0.f;
  if (t < 128) {
    birr = bih[t]     + bhh[t];
    bizz = bih[t+128] + bhh[t+128];
    bin  = bih[t+256];
    bhn  = bhh[t+256];
    ((f16*)hvv)[t] = (f16)0.f;
  } else if (t < 192) {
    ((f16*)xvv)[t-128] = (f16)xs[(S_-1)*BD_ + brow*D_ + (t-128)];
  }
  __syncthreads();

  #pragma unroll 1
  for (int s = 0; s < S_; ++s) {
    float xnext = 0.f;
    if (s < S_-1 && t >= 128 && t < 192)
      xnext = xs[(S_-2-s)*BD_ + brow*D_ + (t-128)];

    if (kh == 0) {
      float ar = 0.f, az = 0.f, an = 0.f;
      #pragma unroll
      for (int c = 0; c < 12; ++c) {
        h8 a = hvv[c];
        ar = dot8(a, wr[c], ar);
        az = dot8(a, wz[c], az);
        an = dot8(a, wn[c], an);
      }
      P[0][0][jh] = ar; P[0][1][jh] = az; P[0][2][jh] = an;
    } else {
      float ar = 0.f, az = 0.f, anh = 0.f, anx = 0.f;
      #pragma unroll
      for (int c = 0; c < 4; ++c) {
        h8 a = hvv[12 + c];
        ar  = dot8(a, wr[c], ar);
        az  = dot8(a, wz[c], az);
        anh = dot8(a, wn[c], anh);
      }
      #pragma unroll
      for (int c = 0; c < 8; ++c) {
        h8 a = xvv[c];
        ar  = dot8(a, wr[4+c], ar);
        az  = dot8(a, wz[4+c], az);
        anx = dot8(a, wn[4+c], anx);
      }
      P[1][0][jh] = ar; P[1][1][jh] = az; P[1][2][jh] = anh; P[1][3][jh] = anx;
    }
    __syncthreads();

    if (t < 128) {
      float pr  = P[0][0][t] + P[1][0][t];
      float pz  = P[0][1][t] + P[1][1][t];
      float pnh = P[0][2][t] + P[1][2][t];
      float pnx = P[1][3][t];
      float r  = sigm(pr + birr);
      float zg = sigm(pz + bizz);
      float n  = tanh_(pnx + bin + r*(pnh + bhn));
      hmast = (1.f - zg)*n + zg*hmast;
      ((f16*)hvv)[t] = (f16)hmast;
    } else if (t < 192 && s < S_-1) {
      ((f16*)xvv)[t-128] = (f16)xnext;
    }
    __syncthreads();
  }
  if (t < 128) hT[brow*H_ + t] = hmast;
}

// ---------------------------------------------------------------------------
// Encoder head (tiny): 256 blocks x 4 rows.
// ---------------------------------------------------------------------------
__global__ __launch_bounds__(256) void enc_kernel(
    const float* __restrict__ hT, const float* __restrict__ encW,
    const float* __restrict__ encB, const float* __restrict__ qW,
    const float* __restrict__ qB, const float* __restrict__ eps,
    const float* __restrict__ pm, const float* __restrict__ pls,
    float* __restrict__ z0, float* __restrict__ out)
{
  __shared__ float hTl[4][128];
  __shared__ float ctx[4][64];
  __shared__ float ql[4][64];
  const int t = threadIdx.x;
  const int b0 = blockIdx.x * 4;
  const int lb = t >> 6, j = t & 63;

  for (int i = t; i < 512; i += 256) hTl[i>>7][i&127] = hT[b0*H_ + i];
  __syncthreads();

  float acc = encB[j];
  #pragma unroll
  for (int k = 0; k < 128; k += 4) {
    f4 w = *(const f4*)&encW[j*128 + k];
    acc += hTl[lb][k]*w[0] + hTl[lb][k+1]*w[1] + hTl[lb][k+2]*w[2] + hTl[lb][k+3]*w[3];
  }
  ctx[lb][j] = acc;
  __syncthreads();

  float q = qB[j];
  #pragma unroll
  for (int k = 0; k < 64; k += 4) {
    f4 w = *(const f4*)&qW[j*64 + k];
    q += ctx[lb][k]*w[0] + ctx[lb][k+1]*w[1] + ctx[lb][k+2]*w[2] + ctx[lb][k+3]*w[3];
  }
  ql[lb][j] = q;
  __syncthreads();

  float kl = 0.f;
  if (j < 32) {
    float mean = ql[lb][j], ls = ql[lb][j+32];
    z0[(b0+lb)*Z_ + j] = mean + __expf(ls)*eps[(b0+lb)*Z_ + j];
    float pmj = pm[j], plsj = pls[j];
    float dm = mean - pmj;
    kl = plsj - ls + (__expf(2.f*ls) + dm*dm) / (2.f*__expf(2.f*plsj)) - 0.5f;
  }
  #pragma unroll
  for (int s2 = 32; s2 > 0; s2 >>= 1) kl += __shfl_down(kl, s2, 64);
  if (j == 0) atomicAdd(out + 1, kl * (1.f/1024.f));
}

// ---------------------------------------------------------------------------
// SDE: 1024 blocks x 1 batch row, 256 threads, 4 blocks/CU target.
// Role weights unioned into wbig[16] (t<128: fW2 row; 128..191: gW2-half +
// projW; >=192: fW3-half). 3 barriers/step; projection folded into P1.
// ---------------------------------------------------------------------------
__global__ __launch_bounds__(256, 4) void sde_kernel(
    const float* __restrict__ z0, const float* __restrict__ ts,
    const float* __restrict__ dW, const float* __restrict__ xs,
    const float* __restrict__ fW1, const float* __restrict__ fb1,
    const float* __restrict__ fW2, const float* __restrict__ fb2,
    const float* __restrict__ fW3, const float* __restrict__ fb3,
    const float* __restrict__ gW1, const float* __restrict__ gb1,
    const float* __restrict__ gW2, const float* __restrict__ gb2,
    const float* __restrict__ pW, const float* __restrict__ pb,
    float* __restrict__ out)
{
  __shared__ h8 zcv[4];          // z f16 (32)
  __shared__ h8 actv[48];        // f16: h1[0:128], gh[128:256], h2[256:384]
  __shared__ float dpart[64];    // diff k-half partials
  __shared__ float tsL[516];

  const int t    = threadIdx.x;
  const int brow = blockIdx.x;

  // P1 role: row t of [fW1; gW1]
  const float* w1src = (t < 128) ? (fW1 + t*33) : (gW1 + (t-128)*33);
  const float twv = w1src[0];
  const float b1v = (t < 128) ? fb1[t] : gb1[t-128];
  h8 w1z[4];
  #pragma unroll
  for (int c = 0; c < 4; ++c) {          // stride-33 rows: scalar loads, startup only
    h8 w;
    #pragma unroll
    for (int e = 0; e < 8; ++e) w[e] = (f16)w1src[1 + c*8 + e];
    w1z[c] = w;
  }

  // role-unioned weight array (saves ~60 VGPR vs separate arrays)
  h8 wbig[16];
  float b2v = 0.f, pbv = 0.f, b3v = 0.f, gb2v = 0.f;
  int zi = 0, kq = 0, v = 0, pd = 0;
  if (t < 128) {
    const float* p = fW2 + t*H_;
    #pragma unroll
    for (int c = 0; c < 16; ++c) wbig[c] = ld8(p + c*8);
    b2v = fb2[t];
  } else if (t < 192) {
    int u = t - 128; zi = u >> 1; kq = u & 1; pd = u;
    const float* p = gW2 + zi*H_ + kq*64;
    #pragma unroll
    for (int c = 0; c < 8; ++c) wbig[c] = ld8(p + c*8);
    const float* pp = pW + pd*Z_;
    #pragma unroll
    for (int c = 0; c < 4; ++c) wbig[8+c] = ld8(pp + c*8);
    pbv = pb[pd];
  } else {
    v = t - 192; zi = v >> 1; kq = v & 1;
    const float* p = fW3 + zi*H_ + kq*64;
    #pragma unroll
    for (int c = 0; c < 8; ++c) wbig[c] = ld8(p + c*8);
    b3v = fb3[zi]; gb2v = gb2[zi];
  }

  for (int i = t; i < 515; i += 256) tsL[i] = ts[i];
  float zm = 0.f;
  if (t >= 192 && !(v & 1)) {
    zm = z0[brow*Z_ + zi];
    ((f16*)zcv)[zi] = (f16)zm;
  }
  float loss = 0.f;
  __syncthreads();

  #pragma unroll 1
  for (int l = 0; l < NSTEP; ++l) {
    const float tl  = tsL[l];
    const float dt  = tsL[l+1] - tl;
    const float sdt = sqrtf(dt);
    const bool ev = ((l & 1) == 0) && l >= 2 && l <= 512;
    const bool od = ((l & 1) == 1) && l >= 3 && l <= 511;
    float dwv = 0.f;
    if (t >= 192 && !(v & 1)) dwv = dW[(l*B_ + brow)*Z_ + zi];
    float xsv = 0.f;
    if (ev && t >= 128 && t < 192) xsv = xs[((l-2)>>1)*BD_ + brow*D_ + pd];

    // P1: h1/gh row t from zc (zs[l]); projection of zs[l] on threads 128..191
    {
      h8 zr0 = zcv[0], zr1 = zcv[1], zr2 = zcv[2], zr3 = zcv[3];
      float a = fmaf(twv, tl, b1v);
      a = dot8(zr0, w1z[0], a);
      a = dot8(zr1, w1z[1], a);
      a = dot8(zr2, w1z[2], a);
      a = dot8(zr3, w1z[3], a);
      ((f16*)actv)[t] = (f16)fmaxf(a, 0.f);
      if ((ev || od) && t >= 128 && t < 192) {
        float pa = pbv;
        pa = dot8(zr0, wbig[8],  pa);
        pa = dot8(zr1, wbig[9],  pa);
        pa = dot8(zr2, wbig[10], pa);
        pa = dot8(zr3, wbig[11], pa);
        if (ev) { float d2 = pa - xsv; loss = fmaf(d2, d2, loss); }
        else out[2 + (((l-3)>>1)*B_ + brow)*D_ + pd] = pa;
      }
    }
    __syncthreads();   // A

    // P2: h2 (t<128, full k) ; diff partials (128..191, k-half)
    if (t < 128) {
      float c0 = 0.f, c1 = 0.f, c2 = 0.f, c3 = 0.f;
      #pragma unroll
      for (int c = 0; c < 16; c += 4) {
        c0 = dot8(actv[c    ], wbig[c    ], c0);
        c1 = dot8(actv[c + 1], wbig[c + 1], c1);
        c2 = dot8(actv[c + 2], wbig[c + 2], c2);
        c3 = dot8(actv[c + 3], wbig[c + 3], c3);
      }
      float h2v = fmaxf(b2v + (c0 + c1) + (c2 + c3), 0.f);
      ((f16*)actv)[256 + t] = (f16)h2v;
    } else if (t < 192) {
      float c0 = 0.f, c1 = 0.f;
      #pragma unroll
      for (int c = 0; c < 8; c += 2) {
        c0 = dot8(actv[16 + kq*8 + c    ], wbig[c    ], c0);
        c1 = dot8(actv[16 + kq*8 + c + 1], wbig[c + 1], c1);
      }
      dpart[t - 128] = c0 + c1;
    }
    __syncthreads();   // B

    // P3 (t>=192): drift k-half + pair-reduce via shfl; z update on even lanes
    if (t >= 192) {
      float c0 = 0.f, c1 = 0.f;
      #pragma unroll
      for (int c = 0; c < 8; c += 2) {
        c0 = dot8(actv[32 + kq*8 + c    ], wbig[c    ], c0);
        c1 = dot8(actv[32 + kq*8 + c + 1], wbig[c + 1], c1);
      }
      float acc = c0 + c1;
      float other = __shfl_xor(acc, 1, 64);
      if (!(v & 1)) {
        float drift = acc + other + b3v;
        float diff  = dpart[2*zi] + dpart[2*zi + 1] + gb2v;
        zm = fmaf(drift, dt, fmaf(diff, sdt*dwv, zm));
        ((f16*)zcv)[zi] = (f16)zm;
      }
    }
    __syncthreads();   // C
  }

  if (t >= 128 && t < 192) {
    #pragma unroll
    for (int s2 = 32; s2 > 0; s2 >>= 1) loss += __shfl_down(loss, s2, 64);
    if (t == 128) atomicAdd(out + 0, loss * (1.f/16777216.f));
  }
}

extern "C" void kernel_launch(void* const* d_in, const int* in_sizes, int n_in,
                              void* d_out, int out_size, void* d_ws, size_t ws_size,
                              hipStream_t stream) {
  (void)in_sizes; (void)n_in; (void)out_size; (void)ws_size;
  const float* xs   = (const float*)d_in[0];
  const float* ts   = (const float*)d_in[1];
  const float* eps  = (const float*)d_in[2];
  const float* dWp  = (const float*)d_in[3];
  const float* Wih  = (const float*)d_in[4];
  const float* Whh  = (const float*)d_in[5];
  const float* bih  = (const float*)d_in[6];
  const float* bhh  = (const float*)d_in[7];
  const float* encW = (const float*)d_in[8];
  const float* encB = (const float*)d_in[9];
  const float* qW   = (const float*)d_in[10];
  const float* qB   = (const float*)d_in[11];
  const float* fW1  = (const float*)d_in[12];
  const float* fb1  = (const float*)d_in[13];
  const float* fW2  = (const float*)d_in[14];
  const float* fb2  = (const float*)d_in[15];
  const float* fW3  = (const float*)d_in[16];
  const float* fb3  = (const float*)d_in[17];
  const float* gW1  = (const float*)d_in[18];
  const float* gb1  = (const float*)d_in[19];
  const float* gW2  = (const float*)d_in[20];
  const float* gb2  = (const float*)d_in[21];
  const float* pW   = (const float*)d_in[22];
  const float* pb   = (const float*)d_in[23];
  const float* pm   = (const float*)d_in[24];
  const float* pls  = (const float*)d_in[25];

  float* out = (float*)d_out;
  float* ws  = (float*)d_ws;
  float* hT = ws;              // 1024*128 floats
  float* z0 = ws + 131072;     // 1024*32 floats

  hipMemsetAsync(d_out, 0, 2*sizeof(float), stream);
  hipLaunchKernelGGL(gru_kernel, dim3(1024), dim3(256), 0, stream,
                     xs, Wih, Whh, bih, bhh, hT);
  hipLaunchKernelGGL(enc_kernel, dim3(256), dim3(256), 0, stream,
                     hT, encW, encB, qW, qB, eps, pm, pls, z0, out);
  hipLaunchKernelGGL(sde_kernel, dim3(1024), dim3(256), 0, stream,
                     z0, ts, dWp, xs, fW1, fb1, fW2, fb2, fW3, fb3,
                     gW1, gb1, gW2, gb2, pW, pb, out);
}